// Round 6
// baseline (96.947 us; speedup 1.0000x reference)
//
#include <hip/hip_runtime.h>
#include <math.h>

// FSQ: x (64,32768,4) f32 -> z (level-major transposed layout) + code.
// LEVELS = [8,5,5,5], N rows of D=4.
#define N_ROWS 2097152  // 64*32768
#define NPT 4           // rows per thread (float4-coalesced stores need 4)

// Native Clang vector type: accepted by __builtin_nontemporal_store
// (HIP's float4 is a HIP_vector_type class and is rejected).
typedef float floatx4 __attribute__((ext_vector_type(4)));

// Levels replicating np.linspace(-1,1,n,dtype=float32).
__device__ __constant__ float L8[8] = {
    -1.0f,
    (float)(1.0 * (2.0 / 7.0) - 1.0),
    (float)(2.0 * (2.0 / 7.0) - 1.0),
    (float)(3.0 * (2.0 / 7.0) - 1.0),
    (float)(4.0 * (2.0 / 7.0) - 1.0),
    (float)(5.0 * (2.0 / 7.0) - 1.0),
    (float)(6.0 * (2.0 / 7.0) - 1.0),
    1.0f};
__device__ __constant__ float L5[5] = {-1.0f, -0.5f, 0.0f, 0.5f, 1.0f};

// Exact slow-path quant: replicate np argmin |lv[j]-xi| (first-occurrence).
template <int NLEV>
__device__ inline void quant_exact(float xi, const float* __restrict__ lv,
                                   int& idx) {
    float best = fabsf(lv[0] - xi);
    int bi = 0;
#pragma unroll
    for (int j = 1; j < NLEV; ++j) {
        float d = fabsf(lv[j] - xi);
        if (d < best) { best = d; bi = j; }
    }
    idx = bi;
}

// Fast tanh: t = 1 - 2*rcp(exp2(x*2/ln2) + 1).
// v_exp_f32 (~1 ulp) + v_rcp_f32 (~1 ulp) -> abs output error <= ~1e-6.
__device__ __forceinline__ float fast_tanh(float x) {
    float e = __builtin_amdgcn_exp2f(x * 2.88539008177792681472f);  // 2/ln2
    return fmaf(-2.0f, __builtin_amdgcn_rcpf(e + 1.0f), 1.0f);
}

// Guard: |v - rint(v)| > 0.5 - EPS_U => too close to a decision boundary,
// take the exact path. EPS_U = 5e-5 units vs fast-path error <= 3.5e-6 units
// (14x margin), so off-guard indices are provably identical to the reference.
#define GTHR (0.5f - 5e-5f)

__global__ __launch_bounds__(256) void fsq_kernel(const float* __restrict__ x,
                                                  float* __restrict__ out) {
    const int t = blockIdx.x * blockDim.x + threadIdx.x;
    if (t >= N_ROWS / NPT) return;
    const long long n0 = (long long)t * NPT;

    floatx4 xin[NPT];
#pragma unroll
    for (int j = 0; j < NPT; ++j)
        xin[j] = reinterpret_cast<const floatx4*>(x)[n0 + j];

    float k0[NPT], k1[NPT], k2[NPT], k3[NPT];
    float m = 0.0f;  // max boundary proximity over all 16 values

#pragma unroll
    for (int j = 0; j < NPT; ++j) {
        const floatx4 xv = xin[j];
        float v0 = fmaf(fast_tanh(xv.x), 3.5f, 3.5f);
        float v1 = fmaf(fast_tanh(xv.y), 2.0f, 2.0f);
        float v2 = fmaf(fast_tanh(xv.z), 2.0f, 2.0f);
        float v3 = fmaf(fast_tanh(xv.w), 2.0f, 2.0f);
        k0[j] = rintf(v0);
        k1[j] = rintf(v1);
        k2[j] = rintf(v2);
        k3[j] = rintf(v3);
        m = fmaxf(m, fmaxf(fmaxf(fabsf(v0 - k0[j]), fabsf(v1 - k1[j])),
                           fmaxf(fabsf(v2 - k2[j]), fabsf(v3 - k3[j]))));
    }

    // Single per-thread branch: any of the 16 values near a boundary?
    if (m > GTHR) {
#pragma unroll
        for (int j = 0; j < NPT; ++j) {
            const floatx4 xv = xin[j];
            // Exact reference path: f64 tanh (rounds to numpy f32 tanh,
            // verified absmax 0.0 in R1) + exact argmin with f32 levels.
            float xi0 = (float)tanh((double)xv.x);
            float xi1 = (float)tanh((double)xv.y);
            float xi2 = (float)tanh((double)xv.z);
            float xi3 = (float)tanh((double)xv.w);
            int i0, i1, i2, i3;
            quant_exact<8>(xi0, L8, i0);
            quant_exact<5>(xi1, L5, i1);
            quant_exact<5>(xi2, L5, i2);
            quant_exact<5>(xi3, L5, i3);
            k0[j] = (float)i0; k1[j] = (float)i1;
            k2[j] = (float)i2; k3[j] = (float)i3;
        }
    }

    floatx4 z0v, z1v, z2v, z3v, cv;
#pragma unroll
    for (int j = 0; j < NPT; ++j) {
        // q values: dim0 bit-matches L8 via the same double formula it was
        // built from; dims 1-3 exact in f32. st = xi + (q - xi) == q here,
        // within 1 ulp of the reference's f32 st.
        z0v[j] = (float)((double)k0[j] * (2.0 / 7.0) - 1.0);
        z1v[j] = fmaf(k1[j], 0.5f, -1.0f);
        z2v[j] = fmaf(k2[j], 0.5f, -1.0f);
        z3v[j] = fmaf(k3[j], 0.5f, -1.0f);
        // code = i0 + 8*i1 + 40*i2 + 200*i3 (integers <= 999, exact in f32)
        cv[j] = fmaf(200.0f, k3[j], fmaf(40.0f, k2[j], fmaf(8.0f, k1[j], k0[j])));
    }

    // Streams written once, never read: nontemporal 16B stores.
    __builtin_nontemporal_store(z0v, reinterpret_cast<floatx4*>(out + 0ll * N_ROWS) + t);
    __builtin_nontemporal_store(z1v, reinterpret_cast<floatx4*>(out + 1ll * N_ROWS) + t);
    __builtin_nontemporal_store(z2v, reinterpret_cast<floatx4*>(out + 2ll * N_ROWS) + t);
    __builtin_nontemporal_store(z3v, reinterpret_cast<floatx4*>(out + 3ll * N_ROWS) + t);
    __builtin_nontemporal_store(cv,  reinterpret_cast<floatx4*>(out + 4ll * N_ROWS) + t);
}

extern "C" void kernel_launch(void* const* d_in, const int* in_sizes, int n_in,
                              void* d_out, int out_size, void* d_ws, size_t ws_size,
                              hipStream_t stream) {
    const float* x = (const float*)d_in[0];
    float* out = (float*)d_out;
    const int threads = 256;
    const int total = N_ROWS / NPT;
    const int blocks = (total + threads - 1) / threads;
    fsq_kernel<<<blocks, threads, 0, stream>>>(x, out);
}